// Round 7
// baseline (847.915 us; speedup 1.0000x reference)
//
#include <hip/hip_runtime.h>
#include <hip/hip_bf16.h>
#include <math.h>

#define T_TOK 4096
#define H_DIM 1024
#define I_DIM 4096
#define NEXP 8
#define RMAX 8192  // T_TOK * TOP_K

#if __has_builtin(__builtin_amdgcn_global_load_lds)
#define USE_GLL 1
#else
#define USE_GLL 0
#endif

typedef __attribute__((ext_vector_type(4))) float f32x4;
typedef __attribute__((ext_vector_type(8))) short short8;

#if USE_GLL
typedef __attribute__((address_space(1))) const void gconst_t;
typedef __attribute__((address_space(3))) void lds_t;
#endif

static __device__ __forceinline__ short bfc(float f) {
    return __builtin_bit_cast(short, __float2bfloat16(f));
}
static __device__ __forceinline__ short8 cvt8(float4 a, float4 b) {
    short8 r;
    r[0] = bfc(a.x); r[1] = bfc(a.y); r[2] = bfc(a.z); r[3] = bfc(a.w);
    r[4] = bfc(b.x); r[5] = bfc(b.y); r[6] = bfc(b.z); r[7] = bfc(b.w);
    return r;
}

#define W1_CHUNKS (NEXP * I_DIM * H_DIM / 8)  // 4194304 short8 chunks (same for W2)
#define X_CHUNKS  (T_TOK * H_DIM / 8)         // 524288

// ---------------- prep: convert W1/W2/x to bf16, zero counts/cursors ----------------
__global__ __launch_bounds__(256) void prep_kernel(
    const float* __restrict__ W1, const float* __restrict__ W2, const float* __restrict__ x,
    unsigned short* __restrict__ w1b, unsigned short* __restrict__ w2b, unsigned short* __restrict__ xb,
    int* __restrict__ counts)
{
    int stride = gridDim.x * blockDim.x;
    for (int i = blockIdx.x * blockDim.x + threadIdx.x; i < W1_CHUNKS; i += stride) {
        const float4* s1 = (const float4*)W1 + 2 * i;
        ((short8*)w1b)[i] = cvt8(s1[0], s1[1]);
        const float4* s2 = (const float4*)W2 + 2 * i;
        ((short8*)w2b)[i] = cvt8(s2[0], s2[1]);
        if (i < X_CHUNKS) {
            const float4* sx = (const float4*)x + 2 * i;
            ((short8*)xb)[i] = cvt8(sx[0], sx[1]);
        }
        if (i < 16) counts[i] = 0;  // counts[8] + cursors[8] (re-zeroed every launch)
    }
}

// ---------------- router: fp32 logits -> top2 -> renormalized weights ----------------
__global__ __launch_bounds__(256) void router_kernel(
    const float* __restrict__ x, const float* __restrict__ Wg,
    int* __restrict__ sel, float* __restrict__ wtk, int* __restrict__ counts)
{
    __shared__ float wg[NEXP * H_DIM];  // 32 KB
    int tid = threadIdx.x;
    float4* wg4 = (float4*)wg;
    const float4* Wg4 = (const float4*)Wg;
    for (int i = tid; i < NEXP * H_DIM / 4; i += 256) wg4[i] = Wg4[i];
    __syncthreads();

    int wid = tid >> 6, lane = tid & 63;
    int tok = blockIdx.x * 4 + wid;

    float acc[NEXP];
#pragma unroll
    for (int e = 0; e < NEXP; ++e) acc[e] = 0.f;

    const float* xr = x + tok * H_DIM;
#pragma unroll
    for (int it = 0; it < H_DIM / 64; ++it) {
        int h = it * 64 + lane;
        float xv = xr[h];
#pragma unroll
        for (int e = 0; e < NEXP; ++e) acc[e] += xv * wg[e * H_DIM + h];
    }
#pragma unroll
    for (int e = 0; e < NEXP; ++e) {
#pragma unroll
        for (int off = 32; off > 0; off >>= 1)
            acc[e] += __shfl_xor(acc[e], off);
    }
    if (lane == 0) {
        // top-2 with first-index tie-break (matches jax.lax.top_k)
        int e0 = 0; float l0 = acc[0];
#pragma unroll
        for (int e = 1; e < NEXP; ++e) if (acc[e] > l0) { l0 = acc[e]; e0 = e; }
        int e1 = -1; float l1 = -1e30f;
#pragma unroll
        for (int e = 0; e < NEXP; ++e) if (e != e0 && acc[e] > l1) { l1 = acc[e]; e1 = e; }
        float w0 = 1.f / (1.f + expf(l1 - l0));  // renormalized pair weight; softmax denom cancels
        float w1 = 1.f - w0;
        sel[tok * 2 + 0] = e0; sel[tok * 2 + 1] = e1;
        wtk[tok * 2 + 0] = w0; wtk[tok * 2 + 1] = w1;
        atomicAdd(&counts[e0], 1);
        atomicAdd(&counts[e1], 1);
    }
}

// ---------------- offsets: exclusive scan of 8 counts ----------------
__global__ void offsets_kernel(const int* __restrict__ counts, int* __restrict__ offsets) {
    if (threadIdx.x == 0) {
        int s = 0;
        for (int e = 0; e < NEXP; ++e) { offsets[e] = s; s += counts[e]; }
        offsets[NEXP] = s;
    }
}

// ---------------- scatter: compacted per-expert row lists + inverse map ----------------
__global__ void scatter_kernel(const int* __restrict__ sel,
                               const int* __restrict__ offsets, int* __restrict__ cursors,
                               int* __restrict__ rowTok, int* __restrict__ rowOfTok)
{
    int idx = blockIdx.x * blockDim.x + threadIdx.x;
    if (idx >= 2 * T_TOK) return;
    int t = idx >> 1;
    int e = sel[idx];
    int pos = atomicAdd(&cursors[e], 1);
    int row = offsets[e] + pos;
    rowTok[row] = t;
    rowOfTok[idx] = row;
}

// ============ shared GEMM body pieces (128x128 tile, BK=64, 4 waves) ============
// LDS layout: row r (0..127) x 8 slots of 16B; slot s holds global chunk s^(r&7).
// Read side: chunk kchunk lives at slot kchunk^(r&7).  (rule #21 involution)

// ---------------- GEMM1: hbuf = gelu(xb[gather] @ w1b[e]^T + b1[e]) (bf16) ----------------
__global__ __launch_bounds__(256) void gemm1_kernel(
    const unsigned short* __restrict__ xb, const unsigned short* __restrict__ w1b,
    const float* __restrict__ b1,
    const int* __restrict__ offsets, const int* __restrict__ rowTok,
    unsigned short* __restrict__ hbuf)
{
    int e = blockIdx.z;
    int rowBeg = offsets[e], rowEnd = offsets[e + 1];
    int mbase = rowBeg + blockIdx.y * 128;
    if (mbase >= rowEnd) return;
    int ntile = blockIdx.x;

    __shared__ __align__(16) short As[128 * 64];
    __shared__ __align__(16) short Bs[128 * 64];

    int tid = threadIdx.x;
    int wid = tid >> 6, lane = tid & 63;
    int wr = wid >> 1, wc = wid & 1;
    f32x4 acc[4][4] = {};

#if USE_GLL
    // staging maps (k-invariant): instr i, lane -> (row, slot); source chunk = slot ^ (row&7)
    const unsigned short* aSrc[4];
    const unsigned short* bSrc[4];
#pragma unroll
    for (int i = 0; i < 4; ++i) {
        int cc = i * 64 + lane;
        int r = wid * 32 + (cc >> 3);        // tile row 0..127
        int s = cc & 7;                      // dest 16B slot within row
        int chunk = s ^ (r & 7);             // inverse-swizzled source chunk
        int crow = min(mbase + r, rowEnd - 1);
        aSrc[i] = xb + (size_t)rowTok[crow] * H_DIM + chunk * 8;
        bSrc[i] = w1b + (size_t)e * (I_DIM * H_DIM) + (size_t)(ntile * 128 + r) * H_DIM + chunk * 8;
    }
    short* aDst = As + wid * 2048;  // wave-uniform; HW adds lane*16B
    short* bDst = Bs + wid * 2048;
#else
    int srow = tid >> 1, shalf = tid & 1;
    int crow = min(mbase + srow, rowEnd - 1);
    const unsigned short* aBase = xb + (size_t)rowTok[crow] * H_DIM + shalf * 32;
    const unsigned short* bBase = w1b + (size_t)e * (I_DIM * H_DIM) + (size_t)(ntile * 128 + srow) * H_DIM + shalf * 32;
#endif

    for (int kt = 0; kt < H_DIM / 64; ++kt) {
#if USE_GLL
#pragma unroll
        for (int i = 0; i < 4; ++i) {
            __builtin_amdgcn_global_load_lds((gconst_t*)(aSrc[i] + kt * 64), (lds_t*)(aDst + i * 512), 16, 0, 0);
            __builtin_amdgcn_global_load_lds((gconst_t*)(bSrc[i] + kt * 64), (lds_t*)(bDst + i * 512), 16, 0, 0);
        }
        __syncthreads();  // drains vmcnt: tiles resident
#else
        short8 avv[4], bvv[4];
#pragma unroll
        for (int c = 0; c < 4; ++c) {
            avv[c] = ((const short8*)(aBase + kt * 64))[c];
            bvv[c] = ((const short8*)(bBase + kt * 64))[c];
        }
        __syncthreads();
#pragma unroll
        for (int c = 0; c < 4; ++c) {
            int sw = ((shalf * 4 + c) ^ (srow & 7)) << 4;
            *(short8*)((char*)As + srow * 128 + sw) = avv[c];
            *(short8*)((char*)Bs + srow * 128 + sw) = bvv[c];
        }
        __syncthreads();
#endif
#pragma unroll
        for (int ks = 0; ks < 2; ++ks) {
            short8 af[4], bfr[4];
            int kchunk = ks * 4 + (lane >> 4);
#pragma unroll
            for (int m = 0; m < 4; ++m) {
                int r = wr * 64 + m * 16 + (lane & 15);
                af[m] = *(const short8*)((const char*)As + r * 128 + ((kchunk ^ (r & 7)) << 4));
            }
#pragma unroll
            for (int n = 0; n < 4; ++n) {
                int r = wc * 64 + n * 16 + (lane & 15);
                bfr[n] = *(const short8*)((const char*)Bs + r * 128 + ((kchunk ^ (r & 7)) << 4));
            }
#pragma unroll
            for (int m = 0; m < 4; ++m)
#pragma unroll
                for (int n = 0; n < 4; ++n)
                    acc[m][n] = __builtin_amdgcn_mfma_f32_16x16x32_bf16(af[m], bfr[n], acc[m][n], 0, 0, 0);
        }
        __syncthreads();  // reads done before next tile's staging writes
    }

    const float* b1e = b1 + e * I_DIM + ntile * 128;
#pragma unroll
    for (int n = 0; n < 4; ++n) {
        int colL = wc * 64 + n * 16 + (lane & 15);
        float bias = b1e[colL];
        int colG = ntile * 128 + colL;
#pragma unroll
        for (int m = 0; m < 4; ++m) {
            int baseR = mbase + wr * 64 + m * 16 + ((lane >> 4) << 2);
            f32x4 f = acc[m][n];
#pragma unroll
            for (int j = 0; j < 4; ++j) {
                int r = baseR + j;
                if (r < rowEnd) {
                    float v = f[j] + bias;
                    v = 0.5f * v * (1.f + erff(v * 0.70710678118654752f));  // exact GELU
                    hbuf[(size_t)r * I_DIM + colG] = (unsigned short)bfc(v);
                }
            }
        }
    }
}

// ---------------- GEMM2: ybuf[row] = hbuf[row] @ w2b[e]^T + b2[e] (fp32) ----------------
__global__ __launch_bounds__(256) void gemm2_kernel(
    const unsigned short* __restrict__ hbuf, const unsigned short* __restrict__ w2b,
    const float* __restrict__ b2,
    const int* __restrict__ offsets,
    float* __restrict__ ybuf)
{
    int e = blockIdx.z;
    int rowBeg = offsets[e], rowEnd = offsets[e + 1];
    int mbase = rowBeg + blockIdx.y * 128;
    if (mbase >= rowEnd) return;
    int ntile = blockIdx.x;

    __shared__ __align__(16) short As[128 * 64];
    __shared__ __align__(16) short Bs[128 * 64];

    int tid = threadIdx.x;
    int wid = tid >> 6, lane = tid & 63;
    int wr = wid >> 1, wc = wid & 1;
    f32x4 acc[4][4] = {};

#if USE_GLL
    const unsigned short* aSrc[4];
    const unsigned short* bSrc[4];
#pragma unroll
    for (int i = 0; i < 4; ++i) {
        int cc = i * 64 + lane;
        int r = wid * 32 + (cc >> 3);
        int s = cc & 7;
        int chunk = s ^ (r & 7);
        int crow = min(mbase + r, rowEnd - 1);
        aSrc[i] = hbuf + (size_t)crow * I_DIM + chunk * 8;
        bSrc[i] = w2b + (size_t)e * (H_DIM * I_DIM) + (size_t)(ntile * 128 + r) * I_DIM + chunk * 8;
    }
    short* aDst = As + wid * 2048;
    short* bDst = Bs + wid * 2048;
#else
    int srow = tid >> 1, shalf = tid & 1;
    int crow = min(mbase + srow, rowEnd - 1);
    const unsigned short* aBase = hbuf + (size_t)crow * I_DIM + shalf * 32;
    const unsigned short* bBase = w2b + (size_t)e * (H_DIM * I_DIM) + (size_t)(ntile * 128 + srow) * I_DIM + shalf * 32;
#endif

    for (int kt = 0; kt < I_DIM / 64; ++kt) {
#if USE_GLL
#pragma unroll
        for (int i = 0; i < 4; ++i) {
            __builtin_amdgcn_global_load_lds((gconst_t*)(aSrc[i] + kt * 64), (lds_t*)(aDst + i * 512), 16, 0, 0);
            __builtin_amdgcn_global_load_lds((gconst_t*)(bSrc[i] + kt * 64), (lds_t*)(bDst + i * 512), 16, 0, 0);
        }
        __syncthreads();
#else
        short8 avv[4], bvv[4];
#pragma unroll
        for (int c = 0; c < 4; ++c) {
            avv[c] = ((const short8*)(aBase + kt * 64))[c];
            bvv[c] = ((const short8*)(bBase + kt * 64))[c];
        }
        __syncthreads();
#pragma unroll
        for (int c = 0; c < 4; ++c) {
            int sw = ((shalf * 4 + c) ^ (srow & 7)) << 4;
            *(short8*)((char*)As + srow * 128 + sw) = avv[c];
            *(short8*)((char*)Bs + srow * 128 + sw) = bvv[c];
        }
        __syncthreads();
#endif
#pragma unroll
        for (int ks = 0; ks < 2; ++ks) {
            short8 af[4], bfr[4];
            int kchunk = ks * 4 + (lane >> 4);
#pragma unroll
            for (int m = 0; m < 4; ++m) {
                int r = wr * 64 + m * 16 + (lane & 15);
                af[m] = *(const short8*)((const char*)As + r * 128 + ((kchunk ^ (r & 7)) << 4));
            }
#pragma unroll
            for (int n = 0; n < 4; ++n) {
                int r = wc * 64 + n * 16 + (lane & 15);
                bfr[n] = *(const short8*)((const char*)Bs + r * 128 + ((kchunk ^ (r & 7)) << 4));
            }
#pragma unroll
            for (int m = 0; m < 4; ++m)
#pragma unroll
                for (int n = 0; n < 4; ++n)
                    acc[m][n] = __builtin_amdgcn_mfma_f32_16x16x32_bf16(af[m], bfr[n], acc[m][n], 0, 0, 0);
        }
        __syncthreads();
    }

    const float* b2e = b2 + e * H_DIM + ntile * 128;
#pragma unroll
    for (int m = 0; m < 4; ++m) {
        int baseR = mbase + wr * 64 + m * 16 + ((lane >> 4) << 2);
#pragma unroll
        for (int n = 0; n < 4; ++n) {
            int colL = wc * 64 + n * 16 + (lane & 15);
            float bias = b2e[colL];
            int colG = ntile * 128 + colL;
            f32x4 f = acc[m][n];
#pragma unroll
            for (int j = 0; j < 4; ++j) {
                int r = baseR + j;
                if (r < rowEnd)
                    ybuf[(size_t)r * H_DIM + colG] = f[j] + bias;
            }
        }
    }
}

// ---------------- combine: out[t] = w0*ybuf[r0] + w1*ybuf[r1] ----------------
__global__ __launch_bounds__(256) void combine_kernel(
    const float* __restrict__ ybuf, const int* __restrict__ rowOfTok,
    const float* __restrict__ wtk, float* __restrict__ out)
{
    int t = blockIdx.x;
    int r0 = rowOfTok[2 * t], r1 = rowOfTok[2 * t + 1];
    float w0 = wtk[2 * t], w1 = wtk[2 * t + 1];
    const float4* y0 = (const float4*)(ybuf + (size_t)r0 * H_DIM);
    const float4* y1 = (const float4*)(ybuf + (size_t)r1 * H_DIM);
    float4* o = (float4*)(out + (size_t)t * H_DIM);
    int c = threadIdx.x;  // 256 threads × float4 = 1024 floats = H_DIM
    float4 a = y0[c], b = y1[c];
    float4 r;
    r.x = w0 * a.x + w1 * b.x;
    r.y = w0 * a.y + w1 * b.y;
    r.z = w0 * a.z + w1 * b.z;
    r.w = w0 * a.w + w1 * b.w;
    o[c] = r;
}

extern "C" void kernel_launch(void* const* d_in, const int* in_sizes, int n_in,
                              void* d_out, int out_size, void* d_ws, size_t ws_size,
                              hipStream_t stream) {
    const float* x  = (const float*)d_in[0];
    const float* Wg = (const float*)d_in[1];
    const float* W1 = (const float*)d_in[2];
    const float* b1 = (const float*)d_in[3];
    const float* W2 = (const float*)d_in[4];
    const float* b2 = (const float*)d_in[5];
    float* out = (float*)d_out;

    // ---- workspace layout (≈232 MB) ----
    int* sel       = (int*)d_ws;                       // 8192
    float* wtk     = (float*)(sel + 2 * T_TOK);        // 8192
    int* counts    = (int*)(wtk + 2 * T_TOK);          // 8
    int* cursors   = counts + 8;                       // 8
    int* offsets   = cursors + 8;                      // 16 (uses 9)
    int* rowTok    = offsets + 16;                     // 8192
    int* rowOfTok  = rowTok + RMAX;                    // 8192
    unsigned short* xb   = (unsigned short*)(rowOfTok + RMAX);   // 4 Mi bf16 (8 MB)
    unsigned short* w1b  = xb + (size_t)T_TOK * H_DIM;           // 32 Mi bf16 (64 MB)
    unsigned short* w2b  = w1b + (size_t)NEXP * I_DIM * H_DIM;   // 32 Mi bf16 (64 MB)
    unsigned short* hbuf = w2b + (size_t)NEXP * H_DIM * I_DIM;   // 32 Mi bf16 (64 MB)
    float* ybuf          = (float*)(hbuf + (size_t)RMAX * I_DIM); // 8 Mi fp32 (32 MB)

    prep_kernel<<<2048, 256, 0, stream>>>(W1, W2, x, w1b, w2b, xb, counts);
    router_kernel<<<T_TOK / 4, 256, 0, stream>>>(x, Wg, sel, wtk, counts);
    offsets_kernel<<<1, 64, 0, stream>>>(counts, offsets);
    scatter_kernel<<<(2 * T_TOK + 255) / 256, 256, 0, stream>>>(sel, offsets, cursors, rowTok, rowOfTok);
    gemm1_kernel<<<dim3(I_DIM / 128, 64, NEXP), 256, 0, stream>>>(xb, w1b, b1, offsets, rowTok, hbuf);
    gemm2_kernel<<<dim3(H_DIM / 128, 64, NEXP), 256, 0, stream>>>(hbuf, w2b, b2, offsets, ybuf);
    combine_kernel<<<T_TOK, 256, 0, stream>>>(ybuf, rowOfTok, wtk, out);
}